// Round 3
// baseline (115.123 us; speedup 1.0000x reference)
//
#include <hip/hip_runtime.h>
#include <math.h>

#define DIM    4096
#define NB     1024
#define WPB    2                 // waves (= batch items) per block
#define NBLK   (NB / WPB)        // 512 blocks of 128 threads

typedef float v2f __attribute__((ext_vector_type(2)));

// parity of adjacent-bit products within 6 bits (pairs (0,1)..(4,5))
__host__ __device__ constexpr int czP5(int j) {
    return (((j >> 0) & (j >> 1)) ^ ((j >> 1) & (j >> 2)) ^ ((j >> 2) & (j >> 3)) ^
            ((j >> 3) & (j >> 4)) ^ ((j >> 4) & (j >> 5))) & 1;
}

// Fused (Ry*Rx) SU(2) gate on local bit G of a 64-amp register block.
// SCALAR v_fma_f32 form. Measured (rounds 0-2): v_pk_*_f32 on CDNA4 has an
// effective 8-cycle issue interval (FP32 peak = 1 FMA/lane/cyc; packed ops are
// double-pumped), so 8 pk ops/pair = 64 cyc while 16 scalar fma = 32 cyc.
// Accumulation order matches the old pk version exactly (bit-identical output):
//   y0 = ((sc-term, then -cs, then -/+ss, then cc))  etc.
// Coefficients are wave-uniform SGPRs (1 SGPR read per VALU op: legal).
template<int G>
__device__ __forceinline__ void gate_sc(v2f (&x)[64],
                                        float cc, float cs, float ss, float sc) {
#pragma unroll
    for (int p = 0; p < 32; ++p) {
        const int j0 = ((p >> G) << (G + 1)) | (p & ((1 << G) - 1));
        const int j1 = j0 | (1 << G);
        const float x0r = x[j0].x, x0i = x[j0].y;
        const float x1r = x[j1].x, x1i = x[j1].y;

        float tr =  sc * x1i;                      // t = y0
        float ti = -sc * x1r;
        tr = __builtin_fmaf(-cs, x1r, tr);
        ti = __builtin_fmaf(-cs, x1i, ti);
        tr = __builtin_fmaf(-ss, x0i, tr);
        ti = __builtin_fmaf( ss, x0r, ti);
        tr = __builtin_fmaf( cc, x0r, tr);
        ti = __builtin_fmaf( cc, x0i, ti);

        float ur =  ss * x1i;                      // u = y1
        float ui = -ss * x1r;
        ur = __builtin_fmaf( cc, x1r, ur);
        ui = __builtin_fmaf( cc, x1i, ui);
        ur = __builtin_fmaf( sc, x0i, ur);
        ui = __builtin_fmaf(-sc, x0r, ui);
        ur = __builtin_fmaf( cs, x0r, ur);
        ui = __builtin_fmaf( cs, x0i, ui);

        x[j0] = (v2f){tr, ti};
        x[j1] = (v2f){ur, ui};
    }
}

// CZ diagonal: sign = czP5(j) ^ base(j), base selected per compile-time j among
// 4 runtime sign words. XL: X layout (cross term on j bit5), else Y (j bit0).
template<bool XL>
__device__ __forceinline__ void applyCZ(v2f (&x)[64], unsigned w0, unsigned w0s,
                                        unsigned w1, unsigned w1s) {
#pragma unroll
    for (int j = 0; j < 64; ++j) {
        const bool hi = XL ? ((j & 32) != 0) : ((j & 1) != 0);
        const unsigned wo = czP5(j) ? (hi ? w1s : w0s) : (hi ? w1 : w0);
        x[j].x = __uint_as_float(__float_as_uint(x[j].x) ^ wo);
        x[j].y = __uint_as_float(__float_as_uint(x[j].y) ^ wo);
    }
}

#define WAVEWAIT() asm volatile("s_waitcnt lgkmcnt(0)" ::: "memory")

// 6+6 partition: X layout = lane holds amps (lane<<6)|j (j = amp bits 0-5),
// Y layout = lane holds amps (j<<6)|lane. One wave per batch item; all layout
// exchanges are intra-wave 64x64 transposes through a wave-private, XOR-swizzled
// LDS buffer (phys col = col ^ (row&30)) -> zero __syncthreads in the kernel.
// Half-pass schedule (8 x 6 gates): X0|Y0+CZ0|Y1|X1+CZ1|X2|Y2+CZ2|Y3|X3+CZ3.
__global__ __launch_bounds__(128, 1) void qddpm_kernel(
    const float* __restrict__ in_re,
    const float* __restrict__ in_im,
    const float* __restrict__ params,
    const float* __restrict__ uu,
    float* __restrict__ out)
{
    __shared__ v2f S[WPB * DIM];          // 2 x 32 KB = 64 KB, wave-private slices

    const int tid  = threadIdx.x;
    const int w    = tid >> 6;
    const int lane = tid & 63;
    const int b    = blockIdx.x * WPB + w;
    v2f* Sw = S + w * DIM;

    const float uval = uu[b];

    // ---- global -> registers, X layout (contiguous 512 B per lane) ----
    v2f x[64];
    {
        const float4* re4 = (const float4*)(in_re + (size_t)b * DIM + lane * 64);
        const float4* im4 = (const float4*)(in_im + (size_t)b * DIM + lane * 64);
#pragma unroll
        for (int q = 0; q < 16; ++q) {
            const float4 vr = re4[q];
            const float4 vi = im4[q];
            x[4 * q + 0] = (v2f){vr.x, vi.x};
            x[4 * q + 1] = (v2f){vr.y, vi.y};
            x[4 * q + 2] = (v2f){vr.z, vi.z};
            x[4 * q + 3] = (v2f){vr.w, vi.w};
        }
    }

    // ---- per-wave gate coefficients in registers: lane g (g<48) holds gate g's
    // (cc,cs,ss,sc); fetched later via readlane (wave-uniform index -> SGPRs). ----
    float gv0 = 0.f, gv1 = 0.f, gv2 = 0.f, gv3 = 0.f;
    if (lane < 48) {
        const int lay = lane / 12, q = lane - lay * 12;
        float c1, s1, c2, s2;
        sincosf(params[lay * 24 + q] * 0.5f, &s1, &c1);
        sincosf(params[lay * 24 + 12 + q] * 0.5f, &s2, &c2);
        gv0 = c1 * c2; gv1 = c1 * s2; gv2 = s1 * s2; gv3 = s1 * c2;
    }

    // ---- CZ sign words (bit31 xor masks) ----
    const unsigned SGN = 0x80000000u;
    const unsigned ct  = (unsigned)czP5(lane) << 31;           // pairs within lane's 6 bits
    const unsigned sx1 = ct ^ ((unsigned)(lane & 1) << 31);         // X cross: j5 & lane0
    const unsigned sy1 = ct ^ ((unsigned)((lane >> 5) & 1) << 31);  // Y cross: lane5 & j0

#pragma clang loop unroll(disable)
    for (int h = 0; h < 8; ++h) {
        const int  l   = h >> 1;
        const int  hm4 = h & 3;
        const bool isX = (hm4 == 0) || (hm4 == 3);
        const int  cb  = l * 12 + (isX ? 6 : 0);   // gate idx = cb + 5 - G

        // ---- 6 gates on local bits (coeffs broadcast from lane cb+5-G) ----
        float cc, cs, ss, sc;
#define GETP(GL) \
        cc = __int_as_float(__builtin_amdgcn_readlane(__float_as_int(gv0), (GL))); \
        cs = __int_as_float(__builtin_amdgcn_readlane(__float_as_int(gv1), (GL))); \
        ss = __int_as_float(__builtin_amdgcn_readlane(__float_as_int(gv2), (GL))); \
        sc = __int_as_float(__builtin_amdgcn_readlane(__float_as_int(gv3), (GL)))
        GETP(cb + 5); gate_sc<0>(x, cc, cs, ss, sc);
        GETP(cb + 4); gate_sc<1>(x, cc, cs, ss, sc);
        GETP(cb + 3); gate_sc<2>(x, cc, cs, ss, sc);
        GETP(cb + 2); gate_sc<3>(x, cc, cs, ss, sc);
        GETP(cb + 1); gate_sc<4>(x, cc, cs, ss, sc);
        GETP(cb + 0); gate_sc<5>(x, cc, cs, ss, sc);
#undef GETP

        if (h & 1) {
            // CZ for layer l, in the current layout
            if ((h >> 1) & 1) applyCZ<true >(x, ct, ct ^ SGN, sx1, sx1 ^ SGN);
            else              applyCZ<false>(x, ct, ct ^ SGN, sy1, sy1 ^ SGN);
        } else {
            // intra-wave 64x64 transpose, XOR-swizzled: phys col = c ^ (row & 30)
            WAVEWAIT();                              // WAR vs previous reads
            if (((h >> 1) & 1) == 0) {
                // X -> Y: write rows (b128 pairs), read columns (b64)
                {
                    float4* wb = (float4*)((char*)Sw + lane * 512);
                    const unsigned hs = (unsigned)(lane & 30) >> 1;
#pragma unroll
                    for (int c = 0; c < 64; c += 2)
                        wb[(unsigned)(c >> 1) ^ hs] =
                            make_float4(x[c].x, x[c].y, x[c + 1].x, x[c + 1].y);
                }
                WAVEWAIT();
#pragma unroll
                for (int r = 0; r < 64; ++r) {
                    const v2f* rb = (const v2f*)((char*)Sw +
                        (((unsigned)(lane ^ (r & 30))) << 3));
                    x[r] = rb[r * 64];
                }
            } else {
                // Y -> X: write columns (b64), read rows (b128 pairs)
#pragma unroll
                for (int r = 0; r < 64; ++r) {
                    v2f* wb = (v2f*)((char*)Sw +
                        (((unsigned)(lane ^ (r & 30))) << 3));
                    wb[r * 64] = x[r];
                }
                WAVEWAIT();
                {
                    const float4* rb = (const float4*)((char*)Sw + lane * 512);
                    const unsigned hs = (unsigned)(lane & 30) >> 1;
#pragma unroll
                    for (int c = 0; c < 64; c += 2) {
                        const float4 v = rb[(unsigned)(c >> 1) ^ hs];
                        x[c]     = (v2f){v.x, v.y};
                        x[c + 1] = (v2f){v.z, v.w};
                    }
                }
            }
        }
    }

    // ---- probs: final X layout, lane holds amps (lane<<6)|j ; outcome = lane>>2 ----
    v2f acc = (v2f){0.f, 0.f};
#pragma unroll
    for (int j = 0; j < 64; ++j) acc += x[j] * x[j];
    float partial = acc.x + acc.y;
    partial += __shfl_xor(partial, 1);
    partial += __shfl_xor(partial, 2);          // 4-lane outcome groups summed

    float pr[16];
#pragma unroll
    for (int g = 0; g < 16; ++g) pr[g] = __shfl(partial, g * 4);

    // ---- redundant per-lane inverse-CDF sample + output [B, 256, 2] ----
    float cdf[16];
    float a = 0.f;
#pragma unroll
    for (int g = 0; g < 16; ++g) { a += pr[g]; cdf[g] = a; }
    const float thresh = uval * a;
    int m = 0;
#pragma unroll
    for (int g = 15; g >= 0; --g) { if (cdf[g] >= thresh) m = g; }
    float pm = pr[0];
#pragma unroll
    for (int g = 1; g < 16; ++g) { if (m == g) pm = pr[g]; }
    const float rn = 1.0f / sqrtf(pm);

    if ((lane >> 2) == m) {                      // 4 lanes own the collapsed state
        float4* o = (float4*)((float2*)out + (size_t)b * 256 + (lane & 3) * 64);
#pragma unroll
        for (int q = 0; q < 32; ++q)
            o[q] = make_float4(x[2 * q].x * rn, x[2 * q].y * rn,
                               x[2 * q + 1].x * rn, x[2 * q + 1].y * rn);
    }
}

extern "C" void kernel_launch(void* const* d_in, const int* in_sizes, int n_in,
                              void* d_out, int out_size, void* d_ws, size_t ws_size,
                              hipStream_t stream) {
    const float* in_re  = (const float*)d_in[0];
    const float* in_im  = (const float*)d_in[1];
    const float* params = (const float*)d_in[2];
    const float* u      = (const float*)d_in[3];
    float* out = (float*)d_out;
    qddpm_kernel<<<NBLK, 128, 0, stream>>>(in_re, in_im, params, u, out);
}

// Round 4
// 114.971 us; speedup vs baseline: 1.0013x; 1.0013x over previous
//
#include <hip/hip_runtime.h>
#include <math.h>

#define NTOT   12
#define DIM    4096      // 2^12
#define LAYERS 4
#define NB     1024      // batch
#define SPAD   4608      // phys(i) = i + 2*(i>>4); max 4095+510 = 4605

typedef float v2f __attribute__((ext_vector_type(2)));

// Fused (Ry*Rx) SU(2) gate on local bit G of a 16-amp register block.
// SCALAR v_fma_f32 form (16 fma/pair). Rounds 0-3 measured: v_pk_*_f32 on
// CDNA4 is double-pumped (~8-cyc issue interval; FP32 peak = 1 FMA/lane/cyc),
// so 8 pk ops/pair = ~64 cyc while 16 scalar fma = 32 cyc. Accumulation order
// matches the pk version exactly (bit-identical output, validated in R3).
// Coeffs (cc,cs,ss,sc) arrive in VGPRs from the LDS gco[] table.
template<int G>
__device__ __forceinline__ void gate_sc(v2f (&x)[16],
                                        float cc, float cs, float ss, float sc) {
#pragma unroll
    for (int p = 0; p < 8; ++p) {
        const int j0 = ((p >> G) << (G + 1)) | (p & ((1 << G) - 1));
        const int j1 = j0 | (1 << G);
        const float x0r = x[j0].x, x0i = x[j0].y;
        const float x1r = x[j1].x, x1i = x[j1].y;

        float tr =  sc * x1i;                      // y0
        float ti = -sc * x1r;
        tr = __builtin_fmaf(-cs, x1r, tr);
        ti = __builtin_fmaf(-cs, x1i, ti);
        tr = __builtin_fmaf(-ss, x0i, tr);
        ti = __builtin_fmaf( ss, x0r, ti);
        tr = __builtin_fmaf( cc, x0r, tr);
        ti = __builtin_fmaf( cc, x0i, ti);

        float ur =  ss * x1i;                      // y1
        float ui = -ss * x1r;
        ur = __builtin_fmaf( cc, x1r, ur);
        ui = __builtin_fmaf( cc, x1i, ui);
        ur = __builtin_fmaf( sc, x0i, ur);
        ui = __builtin_fmaf(-sc, x0r, ui);
        ur = __builtin_fmaf( cs, x0r, ur);
        ui = __builtin_fmaf( cs, x0i, ui);

        x[j0] = (v2f){tr, ti};
        x[j1] = (v2f){ur, ui};
    }
}

// Apply the 4 gates of one partition-group of one layer.
// gco[base+3]->G0, gco[base+2]->G1, gco[base+1]->G2, gco[base+0]->G3.
__device__ __forceinline__ void apply4(v2f (&x)[16], const float4* gco, int base) {
    float4 c;
    c = gco[base + 3]; gate_sc<0>(x, c.x, c.y, c.z, c.w);
    c = gco[base + 2]; gate_sc<1>(x, c.x, c.y, c.z, c.w);
    c = gco[base + 1]; gate_sc<2>(x, c.x, c.y, c.z, c.w);
    c = gco[base + 0]; gate_sc<3>(x, c.x, c.y, c.z, c.w);
}

// CZ diagonal: flip sign bits via precomputed xor words (0 or 0x80000000).
__device__ __forceinline__ void applyCZ(v2f (&x)[16], const int (&sw)[16]) {
#pragma unroll
    for (int j = 0; j < 16; ++j) {
        x[j].x = __uint_as_float(__float_as_uint(x[j].x) ^ sw[j]);
        x[j].y = __uint_as_float(__float_as_uint(x[j].y) ^ sw[j]);
    }
}

// Padded layout: phys(i) = i + 2*(i>>4). All pass patterns affine in j, 4
// lanes per bank-pair per wave-op; C-partition contiguous 128 B, 16B-aligned.
// Palindrome schedule: C0|B0|A0+CZ+A1|B1|C1+CZ+C2|B2|A2+CZ+A3|B3|C3+CZ
// => 9 LDS passes, 10 barriers. 4 blocks/CU (16 waves/CU) for TLP latency
// hiding -- rounds 1-3 proved 1 wave/SIMD stalls ~60% regardless of ILP.
__global__ __launch_bounds__(256, 4) void qddpm_kernel(
    const float* __restrict__ in_re,
    const float* __restrict__ in_im,
    const float* __restrict__ params,
    const float* __restrict__ uu,
    float* __restrict__ out)
{
    __shared__ v2f    S[SPAD];         // 36 KB, interleaved (re,im), padded layout
    __shared__ float4 gco[48];         // per-gate (cc, cs, ss, sc), g = lay*12+q
    __shared__ float  sprob[16];

    const int b = blockIdx.x;
    const int t = threadIdx.x;
    const float uval = uu[b];

    // per-thread bases (v2f element indices)
    const int baseA = t + 2 * (t >> 4);            // A: S[baseA + 288*j], amp j*256+t
    const int baseB = (t >> 4) * 288 + (t & 15);   // B: S[baseB + 18*j],  amp (t>>4)*256+j*16+(t&15)
    const int baseC = t * 18;                      // C: S[baseC + j],     amp t*16+j (contig)

    v2f x[16];

    // ---- direct global -> registers, C-partition (64 contiguous B per array) ----
    {
        const float4* re4 = (const float4*)(in_re + (size_t)b * DIM + t * 16);
        const float4* im4 = (const float4*)(in_im + (size_t)b * DIM + t * 16);
#pragma unroll
        for (int q = 0; q < 4; ++q) {
            const float4 vr = re4[q];
            const float4 vi = im4[q];
            x[4 * q + 0] = (v2f){vr.x, vi.x};
            x[4 * q + 1] = (v2f){vr.y, vi.y};
            x[4 * q + 2] = (v2f){vr.z, vi.z};
            x[4 * q + 3] = (v2f){vr.w, vi.w};
        }
    }
    if (t < 48) {                        // gate (lay = t/12, q = t%12)
        const int lay = t / 12, q = t - lay * 12;
        float c1, s1, c2, s2;
        sincosf(params[lay * 24 + q] * 0.5f, &s1, &c1);
        sincosf(params[lay * 24 + 12 + q] * 0.5f, &s2, &c2);
        gco[t] = make_float4(c1 * c2, c1 * s2, s1 * s2, s1 * c2); // (cc,cs,ss,sc)
    }

    // CZ sign-bit xor words for both partitions used for CZ application
    int swA[16], swC[16];
#pragma unroll
    for (int j = 0; j < 16; ++j) {
        const int iC = t * 16 + j;           // C-partition amp
        swC[j] = (__popc(iC & (iC >> 1) & 0x7FF) & 1) << 31;
        const int iA = j * 256 + t;          // A-partition amp
        swA[j] = (__popc(iA & (iA >> 1) & 0x7FF) & 1) << 31;
    }

    __syncthreads();                     // (1) gco ready; x stays in registers

    // ---- P1: C gates layer0 (q8..q11) ----
    apply4(x, gco, 0 * 12 + 8);
    {
        float4* dst = (float4*)(S + baseC);
#pragma unroll
        for (int q = 0; q < 8; ++q)
            dst[q] = make_float4(x[2 * q].x, x[2 * q].y, x[2 * q + 1].x, x[2 * q + 1].y);
    }
    __syncthreads();                     // (2)

    // ---- P2: B gates layer0 (q4..q7) ----
#pragma unroll
    for (int j = 0; j < 16; ++j) x[j] = S[baseB + 18 * j];
    apply4(x, gco, 0 * 12 + 4);
#pragma unroll
    for (int j = 0; j < 16; ++j) S[baseB + 18 * j] = x[j];
    __syncthreads();                     // (3)

    // ---- P3: A layer0 + CZ0 + A layer1 ----
#pragma unroll
    for (int j = 0; j < 16; ++j) x[j] = S[baseA + 288 * j];
    apply4(x, gco, 0 * 12 + 0);
    applyCZ(x, swA);
    apply4(x, gco, 1 * 12 + 0);
#pragma unroll
    for (int j = 0; j < 16; ++j) S[baseA + 288 * j] = x[j];
    __syncthreads();                     // (4)

    // ---- P4: B layer1 ----
#pragma unroll
    for (int j = 0; j < 16; ++j) x[j] = S[baseB + 18 * j];
    apply4(x, gco, 1 * 12 + 4);
#pragma unroll
    for (int j = 0; j < 16; ++j) S[baseB + 18 * j] = x[j];
    __syncthreads();                     // (5)

    // ---- P5: C layer1 + CZ1 + C layer2 ----
    {
        const float4* src = (const float4*)(S + baseC);
#pragma unroll
        for (int q = 0; q < 8; ++q) {
            const float4 v = src[q];
            x[2 * q]     = (v2f){v.x, v.y};
            x[2 * q + 1] = (v2f){v.z, v.w};
        }
    }
    apply4(x, gco, 1 * 12 + 8);
    applyCZ(x, swC);
    apply4(x, gco, 2 * 12 + 8);
    {
        float4* dst = (float4*)(S + baseC);
#pragma unroll
        for (int q = 0; q < 8; ++q)
            dst[q] = make_float4(x[2 * q].x, x[2 * q].y, x[2 * q + 1].x, x[2 * q + 1].y);
    }
    __syncthreads();                     // (6)

    // ---- P6: B layer2 ----
#pragma unroll
    for (int j = 0; j < 16; ++j) x[j] = S[baseB + 18 * j];
    apply4(x, gco, 2 * 12 + 4);
#pragma unroll
    for (int j = 0; j < 16; ++j) S[baseB + 18 * j] = x[j];
    __syncthreads();                     // (7)

    // ---- P7: A layer2 + CZ2 + A layer3 ----
#pragma unroll
    for (int j = 0; j < 16; ++j) x[j] = S[baseA + 288 * j];
    apply4(x, gco, 2 * 12 + 0);
    applyCZ(x, swA);
    apply4(x, gco, 3 * 12 + 0);
#pragma unroll
    for (int j = 0; j < 16; ++j) S[baseA + 288 * j] = x[j];
    __syncthreads();                     // (8)

    // ---- P8: B layer3 ----
#pragma unroll
    for (int j = 0; j < 16; ++j) x[j] = S[baseB + 18 * j];
    apply4(x, gco, 3 * 12 + 4);
#pragma unroll
    for (int j = 0; j < 16; ++j) S[baseB + 18 * j] = x[j];
    __syncthreads();                     // (9)

    // ---- P9: C layer3 + CZ3 + probs ----
    {
        const float4* src = (const float4*)(S + baseC);
#pragma unroll
        for (int q = 0; q < 8; ++q) {
            const float4 v = src[q];
            x[2 * q]     = (v2f){v.x, v.y};
            x[2 * q + 1] = (v2f){v.z, v.w};
        }
    }
    apply4(x, gco, 3 * 12 + 8);
    applyCZ(x, swC);
    {
        v2f acc2 = (v2f){0.0f, 0.0f};
#pragma unroll
        for (int j = 0; j < 16; ++j) acc2 += x[j] * x[j];
        float4* dst = (float4*)(S + baseC);
#pragma unroll
        for (int q = 0; q < 8; ++q)
            dst[q] = make_float4(x[2 * q].x, x[2 * q].y, x[2 * q + 1].x, x[2 * q + 1].y);
        // this thread's 16 amps (i = t*16+j) all belong to ancilla outcome t>>4
        float partial = acc2.x + acc2.y;
#pragma unroll
        for (int o = 8; o > 0; o >>= 1)
            partial += __shfl_down(partial, o, 16);
        if ((t & 15) == 0) sprob[t >> 4] = partial;
    }
    __syncthreads();                     // (10) covers S write + sprob

    // ---- redundant per-thread inverse-CDF sample + output [B, 256, 2] ----
    {
        float cdf[16];
        float a = 0.0f;
#pragma unroll
        for (int i = 0; i < 16; ++i) { a += sprob[i]; cdf[i] = a; }
        const float thresh = uval * a;
        int m = 0;
#pragma unroll
        for (int i = 15; i >= 0; --i) { if (cdf[i] >= thresh) m = i; }
        const float rn = 1.0f / sqrtf(sprob[m]);
        const v2f amp = S[baseA + 288 * m];     // phys(m*256 + t), A-pattern
        ((float2*)out)[(size_t)b * 256 + t] = make_float2(amp.x * rn, amp.y * rn);
    }
}

extern "C" void kernel_launch(void* const* d_in, const int* in_sizes, int n_in,
                              void* d_out, int out_size, void* d_ws, size_t ws_size,
                              hipStream_t stream) {
    const float* in_re  = (const float*)d_in[0];
    const float* in_im  = (const float*)d_in[1];
    const float* params = (const float*)d_in[2];
    const float* u      = (const float*)d_in[3];
    float* out = (float*)d_out;
    qddpm_kernel<<<NB, 256, 0, stream>>>(in_re, in_im, params, u, out);
}